// Round 8
// baseline (95.740 us; speedup 1.0000x reference)
//
#include <hip/hip_runtime.h>
#include <math.h>

// Problem constants (from reference): w=0.05, b=5.803, single species.
#define NBINS_MAX 512
#define NMAX      1024                 // atom capacity for LDS staging
#define NFG       4096                 // per-block LDS fine moment grid (u64, 32 KB)
#define GOFF      64                   // fine-grid index offset (covers d < r0)
#define WHALF     98                   // gather half-window in fine bins (6.08 sigma)
#define NSLOT     8                    // u32 slots per coarse bin (32 blocks/slot)
#define SENT32  (NBINS_MAX * NSLOT)    // u32 sentinel index (untouched poison)
constexpr float KW       = 0.05f;
constexpr float INV_KW   = 20.0f;      // 1/w
constexpr float GNORM    = 0.3989422804014327f * INV_KW; // 1/(w*sqrt(2pi))
constexpr float COEFF    = 0.33674809f;    // b*b*0.01
constexpr float FOUR_PI  = 12.566370614359172f;
constexpr float QSCALE     = 1048576.0f;   // 2^20 fixed point for slot flush
constexpr float INV_QSCALE = 1.0f / QSCALE;
constexpr float ES  = 33554432.0f;     // 2^25: M1 (sum e) fixed-point scale
constexpr float E2S = 536870912.0f;    // 2^29: M2 (sum e^2) fixed-point scale
constexpr float A1  = INV_KW / ES;             // m1 -> u*(sum e)/w factor
constexpr float A2  = 0.5f * INV_KW * INV_KW / E2S;  // m2 -> (sum e^2)/(2w^2)

// R20: SINGLE kernel. R19 budget decomposition (vs R13's clean fused
// total-kernel=53.6us = 39.3 fill + 14.3 fixed): controllable = K1+K2+gap+
// extra dispatch ~ 23us, while modeled kernel work is only 6-8us -> the
// per-dispatch overhead (~5-8us) now dominates. Every cause of the earlier
// fused failures is individually fixed and verified:
//   R13 85us serial tail reduce  -> slot design (R14+, proven)
//   R14 65us threadfence wbl2/inv -> vmcnt(0)+relaxed ticket (R15, proven)
//   R15/16 ~20us 12M LDS atomics -> 1 ds_add_u64/pair (R19, proven)
//   R15/16 ~6us tail LDS-pipe (2500 uniform ds_read_b64 wave-ops on 1 CU)
//     -> NEW: tail packs only W into LDS, reads b128 (4 bins/op, ~625
//        wave-ops ~3us), r rebuilt via fmaf -> VALU-bound ~3.6us tail.
// Also delta -> dr/8 (absmax ~ delta^3: 2.4e-4 at dr/4 -> ~3e-5), window
// +-98, NFG=4096 (32 KB; LDS total ~46 KB -> still 1+ block/CU).
// Field margins at dr/8 (fd~3.1e-3): |eq|<=2^25*fd/2=52k (bias 2^17 ok);
// e2q<=(fd/2)^2*2^29=1290; per-block per-fine-bin count<=~20 ->
// M1-sum<=3.7e6<2^29, M2-sum<=26k<2^23, count<2^12. No cross-field carry.
// Ticket: R15's fence-free pattern (flush atomics -> vmcnt(0) -> barrier ->
// t0 RELAXED agent fetch_add; ticket poison base from adjacent untouched
// word). Tail slot reads: agent-scope relaxed atomic loads (coherent point).

__global__ void __launch_bounds__(512)
fused_kernel(const float* __restrict__ pos,
             const float* __restrict__ cell,
             const float* __restrict__ rbins,
             const float* __restrict__ qbins,
             unsigned int* __restrict__ slots,  // [NBINS_MAX*NSLOT]+[sent]+[ticket]
             float*        __restrict__ out,
             int N, int nbins)
{
    __shared__ float sh_pos[3 * NMAX];            // xyz-interleaved positions
    __shared__ unsigned long long sh_fm[NFG];     // packed moments, [8][512] interleave
    __shared__ float sh_W[NBINS_MAX];             // tail: trapz*r*G (W only; r via fma)
    __shared__ unsigned int sh_last;
    const int t  = threadIdx.x;
    const int nb = blockDim.x;             // 512

    // --- stage positions (float4-vectorized), zero fine grid ---
    const int nflt = 3 * N;
    const int nvec = nflt >> 2;
    const float4* p4 = (const float4*)pos;
    for (int v = t; v < nvec; v += nb) {
        const float4 x = p4[v];
        sh_pos[4*v + 0] = x.x;
        sh_pos[4*v + 1] = x.y;
        sh_pos[4*v + 2] = x.z;
        sh_pos[4*v + 3] = x.w;
    }
    for (int s = (nvec << 2) + t; s < nflt; s += nb)
        sh_pos[s] = pos[s];                // tail (absent for N=1024)
    for (int s = t; s < NFG; s += nb)
        sh_fm[s] = 0ull;                   // exact zero -> no poison handling

    // cell and its inverse (wave-uniform, all threads compute)
    float cm[9];
#pragma unroll
    for (int k = 0; k < 9; ++k) cm[k] = cell[k];
    const float a00 = cm[0], a01 = cm[1], a02 = cm[2];
    const float a10 = cm[3], a11 = cm[4], a12 = cm[5];
    const float a20 = cm[6], a21 = cm[7], a22 = cm[8];
    const float det = a00*(a11*a22 - a12*a21)
                    - a01*(a10*a22 - a12*a20)
                    + a02*(a10*a21 - a11*a20);
    const float id = 1.0f / det;
    float im[9];
    im[0] = (a11*a22 - a12*a21)*id;
    im[1] = (a02*a21 - a01*a22)*id;
    im[2] = (a01*a12 - a02*a11)*id;
    im[3] = (a12*a20 - a10*a22)*id;
    im[4] = (a00*a22 - a02*a20)*id;
    im[5] = (a02*a10 - a00*a12)*id;
    im[6] = (a10*a21 - a11*a20)*id;
    im[7] = (a01*a20 - a00*a21)*id;
    im[8] = (a00*a11 - a01*a10)*id;

    const float r0     = rbins[0];
    const float rend   = rbins[nbins - 1];
    const float minb   = r0   - 3.0f * KW;   // reference's in_win gate
    const float maxb   = rend + 3.0f * KW;
    const float dr     = (rend - r0) / (float)(nbins - 1); // linspace spacing
    const float fdelta = 0.125f * dr;                      // fine grid: dr/8
    const float inv_fd = 1.0f / fdelta;

    __syncthreads();

    // --- pair phase: TWO row-pairs per block; ONE ds_add_u64 per pair ---
    const int nrp = (N + 1) / 2;
    const int rp0 = 2 * blockIdx.x;

    auto do_rowpair = [&](int rp) {
        const int A    = rp;
        const int B    = N - 1 - rp;
        const int cntA = N - 1 - A;
        const int cntB = (B != A) ? A : 0;   // guard odd-N center row
        const int tot  = cntA + cntB;
        for (int p = t; p < tot; p += nb) {
            int i, j;
            if (p < cntA) { i = A; j = A + 1 + p; }
            else          { i = B; j = B + 1 + (p - cntA); }

            const float dx = sh_pos[3*j + 0] - sh_pos[3*i + 0];
            const float dy = sh_pos[3*j + 1] - sh_pos[3*i + 1];
            const float dz = sh_pos[3*j + 2] - sh_pos[3*i + 2];
            float fx = dx*im[0] + dy*im[3] + dz*im[6];
            float fy = dx*im[1] + dy*im[4] + dz*im[7];
            float fz = dx*im[2] + dy*im[5] + dz*im[8];
            fx -= rintf(fx); fy -= rintf(fy); fz -= rintf(fz);   // min image
            const float mx = fx*cm[0] + fy*cm[3] + fz*cm[6];
            const float my = fx*cm[1] + fy*cm[4] + fz*cm[7];
            const float mz = fx*cm[2] + fy*cm[5] + fz*cm[8];
            const float d  = sqrtf(mx*mx + my*my + mz*mz + 1e-10f);

            if (d > minb && d < maxb) {
                const int   gi = (int)rintf((d - r0) * inv_fd) + GOFF; // [16,3290]
                const float e  = d - fmaf((float)(gi - GOFF), fdelta, r0); // |e|<=fd/2
                const int   eq  = (int)rintf(e * ES);            // |eq| <= ~52k
                const unsigned int e2q = (unsigned int)rintf(e * e * E2S); // <= ~1290
                const unsigned long long val =
                      (1ull << 52)
                    | ((unsigned long long)e2q << 29)
                    | (unsigned long long)(unsigned int)(eq + 131072);
                const int addr = ((gi & 7) << 9) | (gi >> 3);    // [8][512] interleave
                atomicAdd(&sh_fm[addr], val);                    // ds_add_u64
            }
        }
    };
    do_rowpair(rp0);
    if (rp0 + 1 < nrp) do_rowpair(rp0 + 1);

    __syncthreads();

    // --- gather: lane t owns coarse bin k=t; conflict-free ds_read_b64 ---
    if (t < nbins) {
        const int   k  = t;
        const float dw = fdelta * INV_KW;  // u-step per fine bin (~0.062)
        float u = (float)WHALF * dw;       // 6.08 sigma, walks down
        float e = __expf(-0.5f * u * u);
        float g = __expf(fmaf(u, dw, -0.5f * dw * dw));  // phi-step ratio
        const float m = __expf(-dw * dw);                // ratio-of-ratio
        float acc = 0.0f;
        const int gbase = 8 * k + GOFF - WHALF;          // >= -34+64 > 0 for k>=0
#pragma unroll 4
        for (int it = 0; it <= 2 * WHALF; ++it) {
            const int gi   = gbase + it;                 // < 8*511+64+98 guard by NFG
            const int addr = ((gi & 7) << 9) | (gi >> 3);
            const unsigned long long v = sh_fm[addr];
            const unsigned int cntu = (unsigned int)(v >> 52);
            const float cnt = (float)cntu;
            const float m2  = (float)(unsigned int)((v >> 29) & 0x7FFFFFu);
            const float m1  = (float)((int)((unsigned int)v & 0x1FFFFFFFu)
                                      - (int)(cntu << 17));
            const float term = fmaf(u * A1, m1,
                               fmaf(fmaf(u, u, -1.0f) * A2, m2, cnt));
            acc = fmaf(term, e, acc);
            e *= g; g *= m;                // phi recurrence (2 mul/iter)
            u -= dw;
        }
        // flush: one u32 slot atomic per bin (signed fixed point; wrap exact)
        const int slot = blockIdx.x & (NSLOT - 1);
        const int q = (int)rintf(acc * QSCALE);
        if (q) atomicAdd(&slots[k * NSLOT + slot], (unsigned int)q);
    }

    // --- fence-free release + ticket (R15 pattern, proven) ---
    asm volatile("s_waitcnt vmcnt(0)" ::: "memory");  // my atomics acked at MALL
    __syncthreads();
    if (t == 0) {
        const unsigned int old = __hip_atomic_fetch_add(
            &slots[SENT32 + 1], 1u,
            __ATOMIC_RELAXED, __HIP_MEMORY_SCOPE_AGENT);   // relaxed: no wbl2/inv
        const unsigned int tb  = __hip_atomic_load(
            &slots[SENT32],
            __ATOMIC_RELAXED, __HIP_MEMORY_SCOPE_AGENT);   // untouched poison word
        sh_last = ((old - tb) == (unsigned int)(gridDim.x - 1)) ? 1u : 0u;
    }
    __syncthreads();
    if (!sh_last) return;                  // all non-last blocks exit here

    // =================== tail (one block, minimized) ======================
    const unsigned int base = __hip_atomic_load(
        &slots[SENT32], __ATOMIC_RELAXED, __HIP_MEMORY_SCOPE_AGENT);
    const float vol     = fabsf(det);
    const float n_pairs = 0.5f * (float)N * (float)(N - 1);
    const float rho     = (float)N / vol;
    const float pref    = (vol / n_pairs) * GNORM;

    // slots -> G -> W (LDS holds ONLY W; r rebuilt via fmaf in S/F loop)
    const unsigned long long* s64 = (const unsigned long long*)slots;
    if (t < nbins) {
        long long tot = 0;
#pragma unroll
        for (int s = 0; s < 4; ++s) {      // 4 u64 atomic loads = 8 u32 slots
            const unsigned long long v = __hip_atomic_load(
                &s64[t * 4 + s], __ATOMIC_RELAXED, __HIP_MEMORY_SCOPE_AGENT);
            tot += (int)((unsigned int)v - base);          // unsigned wrap, sign
            tot += (int)((unsigned int)(v >> 32) - base);
        }
        const float summed = (float)tot * INV_QSCALE;
        const float rk = fmaf((float)t, dr, r0);           // == rbins[t] +-1ulp
        const float g  = pref * summed / (FOUR_PI * rk * rk);
        const float G  = COEFF * (g - 1.0f);
        out[t] = G;                                        // G(r)
        const float wk = (t == 0 || t == nbins - 1) ? 0.5f * dr : dr;
        sh_W[t] = wk * rk * G;                             // trapz weight * r * G
    }
    __syncthreads();

    // S(Q), F(Q): thread t owns q; b128 W-reads (4 bins/op, broadcast addr)
    if (t < nbins) {
        const float q    = qbins[t];
        const float qinv = 1.0f / (q + 1e-10f);
        float acc = 0.0f;
        const float4* W4 = (const float4*)sh_W;
        const int n4 = nbins >> 2;
#pragma unroll 4
        for (int b = 0; b < n4; ++b) {
            const float4 w = W4[b];                        // uniform addr: broadcast
            const float rb = fmaf((float)(4*b), dr, r0);
            acc = fmaf(w.x, __sinf(q * rb),                    acc);
            acc = fmaf(w.y, __sinf(q * fmaf(1.0f, dr, rb)),    acc);
            acc = fmaf(w.z, __sinf(q * fmaf(2.0f, dr, rb)),    acc);
            acc = fmaf(w.w, __sinf(q * fmaf(3.0f, dr, rb)),    acc);
        }
        for (int k = n4 << 2; k < nbins; ++k)              // generic tail
            acc = fmaf(sh_W[k], __sinf(q * fmaf((float)k, dr, r0)), acc);
        const float S = 1.0f + FOUR_PI * rho * acc * qinv;
        out[nbins + t]     = S;                            // S(Q)
        out[2 * nbins + t] = q * (S - 1.0f);               // F(Q)
    }
}

// ---------------------------------------------------------------------------
extern "C" void kernel_launch(void* const* d_in, const int* in_sizes, int n_in,
                              void* d_out, int out_size, void* d_ws, size_t ws_size,
                              hipStream_t stream)
{
    const float* pos   = (const float*)d_in[0];  // (N,3) f32
    const float* cell  = (const float*)d_in[1];  // (3,3) f32
    const float* rbins = (const float*)d_in[2];  // (nbins,) f32
    const float* qbins = (const float*)d_in[3];  // (nbins,) f32
    float* out = (float*)d_out;                  // (3, nbins) f32

    const int N     = in_sizes[0] / 3;
    const int nbins = in_sizes[2];
    const int nrp   = (N + 1) / 2;               // row-pairs
    const int grid  = (nrp + 1) / 2;             // 2 row-pairs per block -> 256

    unsigned int* slots = (unsigned int*)d_ws;   // [NBINS_MAX*NSLOT]+[sent]+[ticket]

    hipLaunchKernelGGL(fused_kernel, dim3(grid), dim3(512), 0, stream,
                       pos, cell, rbins, qbins, slots, out, N, nbins);
}